// Round 1
// baseline (255.126 us; speedup 1.0000x reference)
//
#include <hip/hip_runtime.h>
#include <hip/hip_bf16.h>
#include <cstdint>

typedef unsigned short ushort_t;
typedef __attribute__((ext_vector_type(8))) short short8;
typedef __attribute__((ext_vector_type(4))) short short4v;
typedef __attribute__((ext_vector_type(4))) float floatx4;
typedef __attribute__((ext_vector_type(4))) unsigned int uintx4;
typedef __attribute__((ext_vector_type(4))) unsigned short ushort4_t;

#define H_   16
#define DKV_ 64
#define DM_  1024
#define B_   2
#define NQ_  2048
#define NK_  2048

// fp32 -> bf16 round-to-nearest-even
__device__ __forceinline__ unsigned short f2bf(float f) {
  union { float f; unsigned int u; } v; v.f = f;
  unsigned int u = v.u;
  return (unsigned short)((u + 0x7fffu + ((u >> 16) & 1u)) >> 16);
}

// Trans ops via compiler-visible intrinsics (NOT inline asm) — R5-proven.
__device__ __forceinline__ float fexp2(float x) { return __builtin_amdgcn_exp2f(x); }
__device__ __forceinline__ float frcp(float x)  { return __builtin_amdgcn_rcpf(x); }

// packed fp32x2 -> bf16x2 (RTNE). No builtin on gfx950; asm is T12-proven in attn.
__device__ __forceinline__ unsigned int cvt_pk_bf16(float lo, float hi) {
  unsigned int r;
  asm("v_cvt_pk_bf16_f32 %0, %1, %2" : "=v"(r) : "v"(lo), "v"(hi));
  return r;
}

__device__ __forceinline__ floatx4 mfma16(short8 a, short8 b, floatx4 c) {
  return __builtin_amdgcn_mfma_f32_16x16x32_bf16(a, b, c, 0, 0, 0);
}

// async global->LDS, 16B per lane; LDS dest = wave-uniform base + lane*16
__device__ __forceinline__ void gload_lds16(const ushort_t* g, ushort_t* l) {
  __builtin_amdgcn_global_load_lds(
      (const __attribute__((address_space(1))) void*)g,
      (__attribute__((address_space(3))) void*)l, 16, 0, 0);
}

// ---------------- cast kernels (R7-proven) --------------------------------
__global__ __launch_bounds__(256) void cast_x_kernel(
    const float* __restrict__ q, const float* __restrict__ k,
    const float* __restrict__ v, ushort_t* __restrict__ dst)
{
  const int t = blockIdx.y;
  const float* src = (t == 0) ? q : (t == 1) ? k : v;
  ushort_t* d = dst + (size_t)t * 4096 * 1024;
  const int gid = blockIdx.x * 256 + threadIdx.x;
  #pragma unroll
  for (int u = 0; u < 8; u++) {
    const int i4 = u * 131072 + gid;
    floatx4 f = ((const floatx4*)src)[i4];
    ushort4_t o;
    #pragma unroll
    for (int e = 0; e < 4; e++) o[e] = f2bf(f[e]);
    *(ushort4_t*)&d[(size_t)i4 * 4] = o;
  }
}

__global__ __launch_bounds__(256) void cast_wt_kernel(
    const float* __restrict__ Wq, const float* __restrict__ Wk,
    const float* __restrict__ Wv, ushort_t* __restrict__ WtAll)
{
  __shared__ ushort_t tile[32][33];
  const int t = blockIdx.z;
  const float* W = (t == 0) ? Wq : (t == 1) ? Wk : Wv;
  ushort_t* Wt = WtAll + (size_t)t * 1024 * 1024;
  const int n0 = blockIdx.x * 32, k0 = blockIdx.y * 32;
  const int tid = threadIdx.x, r = tid >> 3, c4 = (tid & 7) * 4;
  floatx4 f = *(const floatx4*)&W[(size_t)(k0 + r) * 1024 + n0 + c4];
  #pragma unroll
  for (int e = 0; e < 4; e++) tile[r][c4 + e] = f2bf(f[e]);
  __syncthreads();
  ushort4_t o;
  #pragma unroll
  for (int e = 0; e < 4; e++) o[e] = tile[c4 + e][r];
  *(ushort4_t*)&Wt[(size_t)(n0 + r) * 1024 + k0 + c4] = o;
}

// ---------------- proj v2 (R7-proven, byte-identical) ---------------------
__global__ __launch_bounds__(256, 2) void proj_kernel2(
    const ushort_t* __restrict__ Xbf, const ushort_t* __restrict__ WtAll,
    const float* __restrict__ bq, const float* __restrict__ bk,
    const float* __restrict__ bv,
    ushort_t* __restrict__ Qb, ushort_t* __restrict__ Kb, ushort_t* __restrict__ Vt)
{
  const int mode = blockIdx.z;
  const ushort_t* X  = Xbf  + (size_t)mode * 4096 * 1024;
  const ushort_t* Wt = WtAll + (size_t)mode * 1024 * 1024;
  const float* bias  = (mode == 0) ? bq : (mode == 1) ? bk : bv;
  ushort_t* dst      = (mode == 0) ? Qb : (mode == 1) ? Kb : Vt;

  __shared__ ushort_t SM[8192];
  ushort_t* SA = SM;
  ushort_t* SB = SM + 4096;

  const int tid = threadIdx.x, lane = tid & 63, wid = tid >> 6;
  const int c = lane & 15, g = lane >> 4;
  const int m0 = blockIdx.y * 128, n0 = blockIdx.x * 128;
  const int wm = wid & 1, wn = wid >> 1, mb = wm * 64, nb = wn * 64;
  const int srow = lane >> 2;
  const int schunk = (lane & 3) * 8;

  floatx4 acc[4][4];
  #pragma unroll
  for (int i = 0; i < 4; i++)
    #pragma unroll
    for (int j = 0; j < 4; j++) acc[i][j] = floatx4{0.f, 0.f, 0.f, 0.f};

  for (int k0 = 0; k0 < DM_; k0 += 32) {
    __syncthreads();
    #pragma unroll
    for (int u = 0; u < 2; u++) {
      const int t = wid * 2 + u;
      gload_lds16(&X [(size_t)(m0 + t * 16 + srow) * 1024 + k0 + schunk], &SA[t * 512]);
      gload_lds16(&Wt[(size_t)(n0 + t * 16 + srow) * 1024 + k0 + schunk], &SB[t * 512]);
    }
    __syncthreads();

    short8 af[4], bfr[4];
    #pragma unroll
    for (int i = 0; i < 4; i++) af[i]  = *(const short8*)&SA[(mb + i * 16 + c) * 32 + g * 8];
    #pragma unroll
    for (int j = 0; j < 4; j++) bfr[j] = *(const short8*)&SB[(nb + j * 16 + c) * 32 + g * 8];
    #pragma unroll
    for (int i = 0; i < 4; i++)
      #pragma unroll
      for (int j = 0; j < 4; j++) acc[i][j] = mfma16(af[i], bfr[j], acc[i][j]);
  }

  __syncthreads();
  const float scale = (mode == 0) ? 0.18033688011112042f : 1.0f;
  ushort_t* EP = SM + wid * 2048;
  const int hh = (n0 + nb) >> 6;

  if (mode != 2) {
    for (int jj = 0; jj < 2; jj++) {
      #pragma unroll
      for (int jt = 0; jt < 2; jt++) {
        const int j = jj * 2 + jt;
        const float bb = bias[n0 + nb + j * 16 + c];
        #pragma unroll
        for (int i = 0; i < 4; i++)
          #pragma unroll
          for (int r = 0; r < 4; r++)
            EP[(i * 16 + g * 4 + r) * 32 + jt * 16 + c] =
                f2bf((acc[i][j][r] + bb) * scale);
      }
      #pragma unroll
      for (int u = 0; u < 8; u++) {
        const int rowl = u * 8 + (lane >> 3);
        ushort4_t vv = *(ushort4_t*)&EP[rowl * 32 + (lane & 7) * 4];
        const int rowg = m0 + mb + rowl;
        const int bb2 = rowg >> 11, nn = rowg & 2047;
        *(ushort4_t*)&dst[((size_t)(bb2 * H_ + hh) * NQ_ + nn) * DKV_ +
                          jj * 32 + (lane & 7) * 4] = vv;
      }
    }
  } else {
    const int bb2 = (m0 + mb) >> 11, nloc = (m0 + mb) & 2047;
    for (int j = 0; j < 4; j++) {
      const float bb = bias[n0 + nb + j * 16 + c];
      #pragma unroll
      for (int i = 0; i < 4; i++) {
        ushort4_t pk;
        #pragma unroll
        for (int r = 0; r < 4; r++) pk[r] = f2bf(acc[i][j][r] + bb);
        *(ushort4_t*)&EP[c * 72 + i * 16 + g * 4] = pk;
      }
      const int d0 = j * 16;
      #pragma unroll
      for (int u = 0; u < 2; u++) {
        const int coll = u * 8 + (lane >> 3);
        short8 vv = *(const short8*)&EP[coll * 72 + (lane & 7) * 8];
        *(short8*)&dst[((size_t)(bb2 * H_ + hh) * DKV_ + d0 + coll) * NK_ +
                       nloc + (lane & 7) * 8] = vv;
      }
    }
  }
}

// ---------------- proj fallback (R2/R5-proven) ----------------------------
constexpr int LDT = 40;
__global__ __launch_bounds__(256, 2) void proj_kernel_fb(
    const float* __restrict__ Xq, const float* __restrict__ Xk, const float* __restrict__ Xv,
    const float* __restrict__ Wq, const float* __restrict__ Wk, const float* __restrict__ Wv,
    const float* __restrict__ bq, const float* __restrict__ bk, const float* __restrict__ bv,
    ushort_t* __restrict__ Qb, ushort_t* __restrict__ Kb, ushort_t* __restrict__ Vt)
{
  const int mode = blockIdx.z;
  const float* X    = (mode == 0) ? Xq : (mode == 1) ? Xk : Xv;
  const float* W    = (mode == 0) ? Wq : (mode == 1) ? Wk : Wv;
  const float* bias = (mode == 0) ? bq : (mode == 1) ? bk : bv;
  ushort_t* dst     = (mode == 0) ? Qb : (mode == 1) ? Kb : Vt;

  __shared__ ushort_t Asm[128 * LDT];
  __shared__ ushort_t Bsm[128 * LDT];

  const int tid = threadIdx.x, lane = tid & 63, wid = tid >> 6;
  const int m0 = blockIdx.y * 128, n0 = blockIdx.x * 128;
  const int c = lane & 15, g = lane >> 4;
  const int wm = wid & 1, wn = wid >> 1, mb = wm * 64, nb = wn * 64;

  floatx4 acc[4][4];
  #pragma unroll
  for (int i = 0; i < 4; i++)
    #pragma unroll
    for (int j = 0; j < 4; j++) acc[i][j] = floatx4{0.f, 0.f, 0.f, 0.f};

  const int ar = tid >> 1, ah = tid & 1;
  const int bn = tid & 127, bh2 = tid >> 7;

  for (int k0 = 0; k0 < DM_; k0 += 32) {
    const floatx4* ap = (const floatx4*)(X + (size_t)(m0 + ar) * DM_ + k0 + ah * 16);
    floatx4 av0 = ap[0], av1 = ap[1], av2 = ap[2], av3 = ap[3];
    const float* wp = W + (size_t)(k0 + bh2 * 16) * 1024 + n0 + bn;
    float wv[16];
    #pragma unroll
    for (int j = 0; j < 16; j++) wv[j] = wp[j * 1024];
    short8 pa0, pa1, pb0, pb1;
    #pragma unroll
    for (int j = 0; j < 4; j++) {
      pa0[j] = (short)f2bf(av0[j]); pa0[4 + j] = (short)f2bf(av1[j]);
      pa1[j] = (short)f2bf(av2[j]); pa1[4 + j] = (short)f2bf(av3[j]);
    }
    #pragma unroll
    for (int j = 0; j < 8; j++) { pb0[j] = (short)f2bf(wv[j]); pb1[j] = (short)f2bf(wv[8 + j]); }
    __syncthreads();
    *(short8*)&Asm[ar * LDT + ah * 16]      = pa0;
    *(short8*)&Asm[ar * LDT + ah * 16 + 8]  = pa1;
    *(short8*)&Bsm[bn * LDT + bh2 * 16]     = pb0;
    *(short8*)&Bsm[bn * LDT + bh2 * 16 + 8] = pb1;
    __syncthreads();
    short8 af[4], bfr[4];
    #pragma unroll
    for (int i = 0; i < 4; i++) af[i]  = *(const short8*)&Asm[(mb + i * 16 + c) * LDT + g * 8];
    #pragma unroll
    for (int j = 0; j < 4; j++) bfr[j] = *(const short8*)&Bsm[(nb + j * 16 + c) * LDT + g * 8];
    #pragma unroll
    for (int i = 0; i < 4; i++)
      #pragma unroll
      for (int j = 0; j < 4; j++) acc[i][j] = mfma16(af[i], bfr[j], acc[i][j]);
  }
  #pragma unroll
  for (int j = 0; j < 4; j++) {
    const int col = n0 + nb + j * 16 + c;
    const float bv_ = bias[col];
    const int h = col >> 6, d = col & 63;
    #pragma unroll
    for (int i = 0; i < 4; i++)
      #pragma unroll
      for (int r = 0; r < 4; r++) {
        const int row = m0 + mb + i * 16 + g * 4 + r;
        const int b = row >> 11, n = row & 2047;
        float v = acc[i][j][r] + bv_;
        if (mode == 0) {
          v *= 0.18033688011112042f;
          dst[((size_t)(b * H_ + h) * NQ_ + n) * DKV_ + d] = f2bf(v);
        } else if (mode == 1) {
          dst[((size_t)(b * H_ + h) * NQ_ + n) * DKV_ + d] = f2bf(v);
        } else {
          dst[((size_t)(b * H_ + h) * DKV_ + d) * NK_ + n] = f2bf(v);
        }
      }
  }
}

// ---------------- attn v5: swapped-QK^T, P stays in registers -------------
// S = mfma(K_frag, Q_frag) puts P at q = c (lane-local), k = jk*16 + 4g + r.
// PV A-fragment wants k = kc*32 + 8g + e at the SAME lane — so permute V's
// k-columns in LDS with sigma(kc*32+8g+e) = (2kc+(e>>2))*16 + 4g + (e&3)
// (bijection, g-term matches the lane's own g). A-frag is then built fully
// in-register from the lane's own P values with 8 v_cvt_pk_bf16_f32/tile.
// Removes per wave-tile: 16 ds_write_b16 + 2 ds_read_b128 + ~64 VALU f2bf,
// and the 18KB P LDS buffer (55KB -> 36.8KB). gp gating loads become 4x
// float4/lane-tile (r-values contiguous along k at row q=c).
__global__ __launch_bounds__(512, 4) void attn_kernel(
    const ushort_t* __restrict__ Qb, const ushort_t* __restrict__ Kb,
    const ushort_t* __restrict__ Vt, const float* __restrict__ gp,
    float* __restrict__ out)
{
  __shared__ ushort_t Ks[2][64 * 72];
  __shared__ ushort_t Vs[2][64 * 72];

  const int tid = threadIdx.x, lane = tid & 63, wid = tid >> 6;  // wid 0..7
  const int c = lane & 15, g = lane >> 4;
  const int h = blockIdx.x, b = blockIdx.z;       // h fastest: gp L2 locality
  const int bh = b * H_ + h;
  const int qw = blockIdx.y * 128 + wid * 16;

  const ushort_t* Qp = Qb + (size_t)bh * NQ_ * DKV_;
  const ushort_t* Kp = Kb + (size_t)bh * NK_ * DKV_;
  const ushort_t* Vp = Vt + (size_t)bh * DKV_ * NK_;
  const float* gpq = gp + (size_t)b * NQ_ * NK_ + (size_t)(qw + c) * NK_;

  // cooperative staging: 512 threads cover 64x64, 1 chunk each for K and V
  const int srow = tid >> 3;                      // 0..63
  const int u    = tid & 7;                       // source 8-chunk index
  const int scol = u * 8;
  // sigma slots for V: source k-run [8u,8u+4) -> slot so_lo.., [8u+4,8u+8) -> so_hi..
  const int so_lo = 32 * (u >> 2) + 8 * ((2 * u) & 3) + 4 * ((u >> 1) & 1);
  const int so_hi = 32 * (u >> 2) + 8 * ((2 * u + 1) & 3) + 4 * ((u >> 1) & 1);

  // Q fragments resident (pre-scaled by log2(e)/8)
  short8 qf[2];
  #pragma unroll
  for (int kc = 0; kc < 2; kc++)
    qf[kc] = *(const short8*)&Qp[(qw + c) * DKV_ + kc * 32 + g * 8];

  // stage tile 0 (V goes in sigma-permuted layout)
  *(short8*)&Ks[0][srow * 72 + scol] = *(const short8*)&Kp[(size_t)srow * DKV_ + scol];
  {
    short8 v8 = *(const short8*)&Vp[(size_t)srow * NK_ + scol];
    short4v vlo, vhi;
    #pragma unroll
    for (int e = 0; e < 4; e++) { vlo[e] = v8[e]; vhi[e] = v8[4 + e]; }
    *(short4v*)&Vs[0][srow * 72 + so_lo] = vlo;
    *(short4v*)&Vs[0][srow * 72 + so_hi] = vhi;
  }
  __syncthreads();

  floatx4 o[4];
  float l = 0.f;
  #pragma unroll
  for (int jd = 0; jd < 4; jd++) o[jd] = floatx4{0.f, 0.f, 0.f, 0.f};

  for (int t = 0; t < NK_ / 64; t++) {
    const int k0 = t * 64;
    const int cur = t & 1, nxt = cur ^ 1;

    // gp gathers: 4 x float4 per lane (row q = c, cols k0 + jk*16 + 4g .. +4)
    floatx4 gpv[4];
    #pragma unroll
    for (int jk = 0; jk < 4; jk++)
      gpv[jk] = *(const floatx4*)&gpq[k0 + jk * 16 + g * 4];

    // issue next tile's staging loads (latency covered by whole body)
    short8 knx;
    short4v vlo, vhi;
    const bool has_next = (t + 1) < NK_ / 64;
    if (has_next) {
      const int k1 = k0 + 64;
      knx = *(const short8*)&Kp[(size_t)(k1 + srow) * DKV_ + scol];
      short8 v8 = *(const short8*)&Vp[(size_t)srow * NK_ + k1 + scol];
      #pragma unroll
      for (int e = 0; e < 4; e++) { vlo[e] = v8[e]; vhi[e] = v8[4 + e]; }
    }

    // S = K Q^T (log2 domain, swapped operands): lane holds q=c, k=jk*16+4g+r
    floatx4 s[4];
    #pragma unroll
    for (int jk = 0; jk < 4; jk++) {
      s[jk] = floatx4{0.f, 0.f, 0.f, 0.f};
      #pragma unroll
      for (int kc = 0; kc < 2; kc++) {
        short8 kf = *(const short8*)&Ks[cur][(jk * 16 + c) * 72 + kc * 32 + g * 8];
        s[jk] = mfma16(kf, qf[kc], s[jk]);
      }
    }

    // p = exp2(s); l += p (ungated); gate by gp; pack A-frags in-register.
    // af[kc] words: w0=pk(p[2kc][0],p[2kc][1]) w1=pk(p[2kc][2],p[2kc][3])
    //               w2=pk(p[2kc+1][0],..)      w3=pk(p[2kc+1][2],..)
    uintx4 afw[2];
    #pragma unroll
    for (int jk = 0; jk < 4; jk++) {
      const float p0 = fexp2(s[jk][0]);
      const float p1 = fexp2(s[jk][1]);
      const float p2 = fexp2(s[jk][2]);
      const float p3 = fexp2(s[jk][3]);
      l += (p0 + p1) + (p2 + p3);
      const unsigned int w0 = cvt_pk_bf16(p0 * gpv[jk][0], p1 * gpv[jk][1]);
      const unsigned int w1 = cvt_pk_bf16(p2 * gpv[jk][2], p3 * gpv[jk][3]);
      afw[jk >> 1][2 * (jk & 1) + 0] = w0;
      afw[jk >> 1][2 * (jk & 1) + 1] = w1;
    }

    // PV: A = in-register P frags, B = sigma-permuted V from LDS
    #pragma unroll
    for (int kc = 0; kc < 2; kc++) {
      const short8 af = __builtin_bit_cast(short8, afw[kc]);
      #pragma unroll
      for (int jd = 0; jd < 4; jd++) {
        short8 vf = *(const short8*)&Vs[cur][(jd * 16 + c) * 72 + kc * 32 + g * 8];
        o[jd] = mfma16(af, vf, o[jd]);
      }
    }

    // commit next tile, then barrier
    if (has_next) {
      *(short8*)&Ks[nxt][srow * 72 + scol] = knx;
      *(short4v*)&Vs[nxt][srow * 72 + so_lo] = vlo;
      *(short4v*)&Vs[nxt][srow * 72 + so_hi] = vhi;
    }
    __syncthreads();
  }

  // l lives per q=c; reduce across the 4 g-groups, then redistribute to the
  // output layout's q = 4g + r via shfl (once per kernel).
  float lf = l;
  lf += __shfl_xor(lf, 16);
  lf += __shfl_xor(lf, 32);
  const float inv = frcp(lf);
  float invr[4];
  #pragma unroll
  for (int r = 0; r < 4; r++) invr[r] = __shfl(inv, g * 4 + r);

  #pragma unroll
  for (int jd = 0; jd < 4; jd++)
    #pragma unroll
    for (int r = 0; r < 4; r++) {
      const int row = qw + g * 4 + r;
      out[(size_t)(b * NQ_ + row) * 1024 + h * 64 + jd * 16 + c] =
          o[jd][r] * invr[r];
    }
}

extern "C" void kernel_launch(void* const* d_in, const int* in_sizes, int n_in,
                              void* d_out, int out_size, void* d_ws, size_t ws_size,
                              hipStream_t stream) {
  const float* queries = (const float*)d_in[0];
  const float* keys    = (const float*)d_in[1];
  const float* values  = (const float*)d_in[2];
  const float* gp      = (const float*)d_in[3];
  // d_in[4] attention_mask: intentionally unused (reference discards it)
  const float* Wq = (const float*)d_in[5];
  const float* bq = (const float*)d_in[6];
  const float* Wk = (const float*)d_in[7];
  const float* bk = (const float*)d_in[8];
  const float* Wv = (const float*)d_in[9];
  const float* bv = (const float*)d_in[10];

  const size_t SZ_QKV = (size_t)3 * B_ * H_ * NQ_ * DKV_;  // shorts
  const size_t SZ_X   = (size_t)3 * 4096 * 1024;
  const size_t SZ_W   = (size_t)3 * 1024 * 1024;
  const size_t NEED   = (SZ_QKV + SZ_X + SZ_W) * sizeof(ushort_t);

  ushort_t* Qb = (ushort_t*)d_ws;                       // [B,H,NQ,64] bf16, pre-scaled
  ushort_t* Kb = Qb + (size_t)B_ * H_ * NQ_ * DKV_;     // [B,H,NK,64] bf16
  ushort_t* Vt = Kb + (size_t)B_ * H_ * NK_ * DKV_;     // [B,H,64,NK] bf16
  float* out = (float*)d_out;

  if (ws_size >= NEED) {
    ushort_t* Xbf = Qb + SZ_QKV;
    ushort_t* Wt  = Xbf + SZ_X;
    cast_x_kernel<<<dim3(512, 3), 256, 0, stream>>>(queries, keys, values, Xbf);
    cast_wt_kernel<<<dim3(32, 32, 3), 256, 0, stream>>>(Wq, Wk, Wv, Wt);
    proj_kernel2<<<dim3(8, 32, 3), 256, 0, stream>>>(
        Xbf, Wt, bq, bk, bv, Qb, Kb, Vt);
  } else {
    proj_kernel_fb<<<dim3(8, 32, 3), 256, 0, stream>>>(
        queries, keys, values, Wq, Wk, Wv, bq, bk, bv, Qb, Kb, Vt);
  }
  attn_kernel<<<dim3(H_, NQ_ / 128, B_), 512, 0, stream>>>(Qb, Kb, Vt, gp, out);
}